// Round 1
// baseline (286.389 us; speedup 1.0000x reference)
//
#include <hip/hip_runtime.h>

typedef _Float16 half8 __attribute__((ext_vector_type(8)));
typedef float f32x4 __attribute__((ext_vector_type(4)));

constexpr int B = 2, L = 2048, S = 2048, H = 16, E = 64, D = 64;
constexpr int BM = 64;   // Q rows per workgroup
constexpr int BN = 64;   // K/V rows per iteration
constexpr int LDT = 72;  // padded LDS leading dim (f16 elems): 2-way bank alias on b128 frag reads

__global__ __launch_bounds__(256, 2)
void fa_kernel(const float* __restrict__ Qg, const float* __restrict__ Kg,
               const float* __restrict__ Vg, const float* __restrict__ Mg,
               float* __restrict__ Og)
{
    __shared__ _Float16 sK[BN][LDT];     // K tile, row-major [s][e]
    __shared__ _Float16 sV[D][LDT];      // V tile, TRANSPOSED [d][s]
    __shared__ _Float16 sP[4][16][LDT];  // per-wave P tile [row][s]

    const int tid  = threadIdx.x;
    const int wave = tid >> 6;
    const int lane = tid & 63;
    const int quad = lane >> 4;
    const int lq   = lane & 15;

    const int b  = blockIdx.y >> 4;   // / H
    const int h  = blockIdx.y & 15;   // % H
    const int q0 = blockIdx.x * BM;

    const int rowStride = H * E;      // 1024 floats (same for Q,K,V,O since E==D)
    const size_t qbase = ((size_t)b * L) * rowStride + h * E;
    const size_t kbase = ((size_t)b * S) * rowStride + h * E;

    // ---- Q fragments (A-operand layout: m=lq, k = ks*32 + quad*8 + j) ----
    half8 qf[2];
    {
        const float* qp = Qg + qbase + (size_t)(q0 + wave*16 + lq) * rowStride + quad*8;
        #pragma unroll
        for (int ks = 0; ks < 2; ++ks)
            #pragma unroll
            for (int j = 0; j < 8; ++j)
                qf[ks][j] = (_Float16)qp[ks*32 + j];
    }

    float mi[4], li[4];
    f32x4 oacc[4];
    #pragma unroll
    for (int r = 0; r < 4; ++r) { mi[r] = -1e30f; li[r] = 0.f; }
    #pragma unroll
    for (int nt = 0; nt < 4; ++nt) oacc[nt] = (f32x4){0.f, 0.f, 0.f, 0.f};

    const float scale = 0.125f;  // 1/sqrt(E)

    for (int s0 = 0; s0 < S; s0 += BN) {
        // ---- stage K (row-major) and V (transposed) tiles into LDS as f16 ----
        #pragma unroll
        for (int i = 0; i < 4; ++i) {
            int idx = i * 256 + tid;        // 0..1023 over 64x16 float4s
            int r  = idx >> 4;              // tile row (s)
            int c  = (idx & 15) * 4;        // col (e/d)
            const float4 kv = *(const float4*)(Kg + kbase + (size_t)(s0 + r) * rowStride + c);
            sK[r][c+0] = (_Float16)kv.x; sK[r][c+1] = (_Float16)kv.y;
            sK[r][c+2] = (_Float16)kv.z; sK[r][c+3] = (_Float16)kv.w;
            const float4 vv = *(const float4*)(Vg + kbase + (size_t)(s0 + r) * rowStride + c);
            sV[c+0][r] = (_Float16)vv.x; sV[c+1][r] = (_Float16)vv.y;
            sV[c+2][r] = (_Float16)vv.z; sV[c+3][r] = (_Float16)vv.w;
        }
        __syncthreads();

        // ---- S = Q K^T  (B-operand = K rows: n=lq, k contiguous) ----
        f32x4 sf[4];
        #pragma unroll
        for (int nt = 0; nt < 4; ++nt) {
            half8 kf0 = *(const half8*)&sK[nt*16 + lq][ 0 + quad*8];
            half8 kf1 = *(const half8*)&sK[nt*16 + lq][32 + quad*8];
            f32x4 acc = (f32x4){0.f, 0.f, 0.f, 0.f};
            acc = __builtin_amdgcn_mfma_f32_16x16x32_f16(qf[0], kf0, acc, 0, 0, 0);
            acc = __builtin_amdgcn_mfma_f32_16x16x32_f16(qf[1], kf1, acc, 0, 0, 0);
            sf[nt] = acc;
        }

        // ---- logits = (scores + mask) * scale; C-layout: row=quad*4+r, col=nt*16+lq ----
        float lg[4][4];
        #pragma unroll
        for (int r = 0; r < 4; ++r) {
            const float* mrow = Mg + (size_t)(q0 + wave*16 + quad*4 + r) * S + s0;
            #pragma unroll
            for (int nt = 0; nt < 4; ++nt)
                lg[nt][r] = (sf[nt][r] + mrow[nt*16 + lq]) * scale;
        }

        // ---- online softmax (row stats live in the 16-lane quad) ----
        #pragma unroll
        for (int r = 0; r < 4; ++r) {
            float m = fmaxf(fmaxf(lg[0][r], lg[1][r]), fmaxf(lg[2][r], lg[3][r]));
            #pragma unroll
            for (int off = 1; off < 16; off <<= 1)
                m = fmaxf(m, __shfl_xor(m, off));
            float mnew  = fmaxf(mi[r], m);
            float alpha = __expf(mi[r] - mnew);
            mi[r] = mnew;
            float rs = 0.f;
            #pragma unroll
            for (int nt = 0; nt < 4; ++nt) {
                float p = __expf(lg[nt][r] - mnew);
                lg[nt][r] = p;
                rs += p;
            }
            #pragma unroll
            for (int off = 1; off < 16; off <<= 1)
                rs += __shfl_xor(rs, off);
            li[r] = li[r] * alpha + rs;
            oacc[0][r] *= alpha; oacc[1][r] *= alpha;
            oacc[2][r] *= alpha; oacc[3][r] *= alpha;
        }

        // ---- P -> LDS (C-layout -> A-operand layout round trip, per-wave region) ----
        #pragma unroll
        for (int nt = 0; nt < 4; ++nt)
            #pragma unroll
            for (int r = 0; r < 4; ++r)
                sP[wave][quad*4 + r][nt*16 + lq] = (_Float16)lg[nt][r];

        // ---- O += P V  (A = P rows from LDS; B = V^T rows: n=d, k=s contiguous) ----
        #pragma unroll
        for (int ks = 0; ks < 2; ++ks) {
            half8 pf = *(const half8*)&sP[wave][lq][ks*32 + quad*8];
            #pragma unroll
            for (int nt = 0; nt < 4; ++nt) {
                half8 vf = *(const half8*)&sV[nt*16 + lq][ks*32 + quad*8];
                oacc[nt] = __builtin_amdgcn_mfma_f32_16x16x32_f16(pf, vf, oacc[nt], 0, 0, 0);
            }
        }
        __syncthreads();
    }

    // ---- epilogue: O /= l, store fp32 [B,L,H,D] ----
    #pragma unroll
    for (int r = 0; r < 4; ++r) {
        float inv = 1.f / li[r];
        float* orow = Og + qbase + (size_t)(q0 + wave*16 + quad*4 + r) * rowStride;
        #pragma unroll
        for (int nt = 0; nt < 4; ++nt)
            orow[nt*16 + lq] = oacc[nt][r] * inv;
    }
}

extern "C" void kernel_launch(void* const* d_in, const int* in_sizes, int n_in,
                              void* d_out, int out_size, void* d_ws, size_t ws_size,
                              hipStream_t stream) {
    const float* Qg = (const float*)d_in[0];
    const float* Kg = (const float*)d_in[1];
    const float* Vg = (const float*)d_in[2];
    const float* Mg = (const float*)d_in[3];
    float* Og = (float*)d_out;
    dim3 grid(L / BM, B * H);  // 32 q-blocks x 32 (b,h)
    fa_kernel<<<grid, 256, 0, stream>>>(Qg, Kg, Vg, Mg, Og);
}

// Round 2
// 241.866 us; speedup vs baseline: 1.1841x; 1.1841x over previous
//
#include <hip/hip_runtime.h>

typedef _Float16 half8 __attribute__((ext_vector_type(8)));
typedef _Float16 half4 __attribute__((ext_vector_type(4)));
typedef float f32x4 __attribute__((ext_vector_type(4)));

constexpr int B = 2, L = 2048, S = 2048, H = 16, E = 64, D = 64;
constexpr int BM = 64;   // Q rows per workgroup
constexpr int BN = 64;   // K/V rows per iteration
constexpr int LDT = 72;  // padded LDS leading dim (f16 elems): 36-dword stride => 4-bank lane step, <=2-way

__global__ __launch_bounds__(256, 2)
void fa_kernel(const float* __restrict__ Qg, const float* __restrict__ Kg,
               const float* __restrict__ Vg, const float* __restrict__ Mg,
               float* __restrict__ Og)
{
    __shared__ _Float16 sK[BN][LDT];     // K tile, row-major [s][e]
    __shared__ _Float16 sV[D][LDT];      // V tile, TRANSPOSED [d][s]
    __shared__ _Float16 sP[4][16][LDT];  // per-wave P tile [row][s]

    const int tid  = threadIdx.x;
    const int wave = tid >> 6;
    const int lane = tid & 63;
    const int quad = lane >> 4;
    const int lq   = lane & 15;

    const int b  = blockIdx.y >> 4;   // / H
    const int h  = blockIdx.y & 15;   // % H
    const int q0 = blockIdx.x * BM;

    const int rowStride = H * E;      // 1024 floats (same for Q,K,V,O since E==D)
    const size_t qbase = ((size_t)b * L) * rowStride + h * E;
    const size_t kbase = ((size_t)b * S) * rowStride + h * E;

    const float scale = 0.125f;  // 1/sqrt(E)

    // ---- Q fragments, pre-scaled (A layout: m=lq, k = ks*32 + quad*8 + j) ----
    half8 qf[2];
    {
        const float* qp = Qg + qbase + (size_t)(q0 + wave*16 + lq) * rowStride + quad*8;
        #pragma unroll
        for (int ks = 0; ks < 2; ++ks)
            #pragma unroll
            for (int j = 0; j < 8; ++j)
                qf[ks][j] = (_Float16)(qp[ks*32 + j] * scale);
    }

    float mi[4], li[4];
    f32x4 oacc[4];
    #pragma unroll
    for (int r = 0; r < 4; ++r) { mi[r] = -1e30f; li[r] = 0.f; }
    #pragma unroll
    for (int nt = 0; nt < 4; ++nt) oacc[nt] = (f32x4){0.f, 0.f, 0.f, 0.f};

    // staging decomposition for the V 4x4 register transpose
    const int db = tid & 15;   // d-block (4 cols)
    const int sb = tid >> 4;   // s-block (4 rows)

    for (int s0 = 0; s0 < S; s0 += BN) {
        // ---- K tile: float4 -> half4, vectorized 8B stores (conflict-free rows) ----
        #pragma unroll
        for (int i = 0; i < 4; ++i) {
            int idx = i * 256 + tid;        // 64x16 float4 chunks
            int r  = idx >> 4;
            int c  = (idx & 15) * 4;
            const float4 kv = *(const float4*)(Kg + kbase + (size_t)(s0 + r) * rowStride + c);
            half4 hk = {(_Float16)kv.x, (_Float16)kv.y, (_Float16)kv.z, (_Float16)kv.w};
            *(half4*)&sK[r][c] = hk;
        }
        // ---- V tile: 4x4 register transpose, half4 stores along s (2-way max) ----
        {
            const float* vp = Vg + kbase + (size_t)(s0 + sb*4) * rowStride + db*4;
            float4 vr[4];
            #pragma unroll
            for (int i = 0; i < 4; ++i)
                vr[i] = *(const float4*)(vp + (size_t)i * rowStride);
            #pragma unroll
            for (int j = 0; j < 4; ++j) {
                half4 hv = { (_Float16)((&vr[0].x)[j]), (_Float16)((&vr[1].x)[j]),
                             (_Float16)((&vr[2].x)[j]), (_Float16)((&vr[3].x)[j]) };
                *(half4*)&sV[db*4 + j][sb*4] = hv;
            }
        }
        __syncthreads();

        // ---- S = Q K^T  (B-operand = K rows: n=lq, k contiguous) ----
        f32x4 sf[4];
        #pragma unroll
        for (int nt = 0; nt < 4; ++nt) {
            half8 kf0 = *(const half8*)&sK[nt*16 + lq][ 0 + quad*8];
            half8 kf1 = *(const half8*)&sK[nt*16 + lq][32 + quad*8];
            f32x4 acc = (f32x4){0.f, 0.f, 0.f, 0.f};
            acc = __builtin_amdgcn_mfma_f32_16x16x32_f16(qf[0], kf0, acc, 0, 0, 0);
            acc = __builtin_amdgcn_mfma_f32_16x16x32_f16(qf[1], kf1, acc, 0, 0, 0);
            sf[nt] = acc;
        }

        // ---- logits = scores_prescaled + scale*mask; C-layout: row=quad*4+r, col=nt*16+lq ----
        float lg[4][4];
        #pragma unroll
        for (int r = 0; r < 4; ++r) {
            const float* mrow = Mg + (size_t)(q0 + wave*16 + quad*4 + r) * S + s0;
            #pragma unroll
            for (int nt = 0; nt < 4; ++nt)
                lg[nt][r] = fmaf(scale, mrow[nt*16 + lq], sf[nt][r]);
        }

        // ---- online softmax (row stats live in the 16-lane quad) ----
        #pragma unroll
        for (int r = 0; r < 4; ++r) {
            float m = fmaxf(fmaxf(lg[0][r], lg[1][r]), fmaxf(lg[2][r], lg[3][r]));
            #pragma unroll
            for (int off = 1; off < 16; off <<= 1)
                m = fmaxf(m, __shfl_xor(m, off));
            float mnew  = fmaxf(mi[r], m);
            float alpha = __expf(mi[r] - mnew);
            mi[r] = mnew;
            float rs = 0.f;
            #pragma unroll
            for (int nt = 0; nt < 4; ++nt) {
                float p = __expf(lg[nt][r] - mnew);
                lg[nt][r] = p;
                rs += p;
            }
            #pragma unroll
            for (int off = 1; off < 16; off <<= 1)
                rs += __shfl_xor(rs, off);
            li[r] = li[r] * alpha + rs;
            oacc[0][r] *= alpha; oacc[1][r] *= alpha;
            oacc[2][r] *= alpha; oacc[3][r] *= alpha;
        }

        // ---- P -> LDS (C-layout -> A-operand layout round trip, per-wave region) ----
        #pragma unroll
        for (int nt = 0; nt < 4; ++nt)
            #pragma unroll
            for (int r = 0; r < 4; ++r)
                sP[wave][quad*4 + r][nt*16 + lq] = (_Float16)lg[nt][r];

        // ---- O += P V  (A = P rows from LDS; B = V^T rows: n=d, k=s contiguous) ----
        #pragma unroll
        for (int ks = 0; ks < 2; ++ks) {
            half8 pf = *(const half8*)&sP[wave][lq][ks*32 + quad*8];
            #pragma unroll
            for (int nt = 0; nt < 4; ++nt) {
                half8 vf = *(const half8*)&sV[nt*16 + lq][ks*32 + quad*8];
                oacc[nt] = __builtin_amdgcn_mfma_f32_16x16x32_f16(pf, vf, oacc[nt], 0, 0, 0);
            }
        }
        __syncthreads();
    }

    // ---- epilogue: O /= l, store fp32 [B,L,H,D] ----
    #pragma unroll
    for (int r = 0; r < 4; ++r) {
        float inv = 1.f / li[r];
        float* orow = Og + qbase + (size_t)(q0 + wave*16 + quad*4 + r) * rowStride;
        #pragma unroll
        for (int nt = 0; nt < 4; ++nt)
            orow[nt*16 + lq] = oacc[nt][r] * inv;
    }
}

extern "C" void kernel_launch(void* const* d_in, const int* in_sizes, int n_in,
                              void* d_out, int out_size, void* d_ws, size_t ws_size,
                              hipStream_t stream) {
    const float* Qg = (const float*)d_in[0];
    const float* Kg = (const float*)d_in[1];
    const float* Vg = (const float*)d_in[2];
    const float* Mg = (const float*)d_in[3];
    float* Og = (float*)d_out;
    dim3 grid(L / BM, B * H);  // 32 q-blocks x 32 (b,h)
    fa_kernel<<<grid, 256, 0, stream>>>(Qg, Kg, Vg, Mg, Og);
}

// Round 3
// 229.260 us; speedup vs baseline: 1.2492x; 1.0550x over previous
//
#include <hip/hip_runtime.h>

typedef _Float16 half8 __attribute__((ext_vector_type(8)));
typedef _Float16 half4 __attribute__((ext_vector_type(4)));
typedef float f32x4 __attribute__((ext_vector_type(4)));

constexpr int B = 2, L = 2048, S = 2048, H = 16, E = 64, D = 64;
constexpr int BM = 64;   // Q rows per workgroup
constexpr int BN = 64;   // K/V rows per iteration
constexpr int LDT = 72;  // padded leading dim (f16): 36-dword row stride

__global__ __launch_bounds__(256, 2)
void fa_kernel(const float* __restrict__ Qg, const float* __restrict__ Kg,
               const float* __restrict__ Vg, const float* __restrict__ Mg,
               float* __restrict__ Og)
{
    __shared__ _Float16 sK[BN][LDT];     // K tile, row-major [s][e]
    __shared__ _Float16 sV[D][LDT];      // V tile, transposed [d][s], XOR-swizzled 16B chunks
    __shared__ _Float16 sP[4][16][LDT];  // per-wave P tile [row][s]

    const int tid  = threadIdx.x;
    const int wave = tid >> 6;
    const int lane = tid & 63;
    const int quad = lane >> 4;
    const int lq   = lane & 15;

    const int b  = blockIdx.y >> 4;   // / H
    const int h  = blockIdx.y & 15;   // % H
    const int q0 = blockIdx.x * BM;

    const int rowStride = H * E;      // 1024 floats
    const size_t qbase = ((size_t)b * L) * rowStride + h * E;
    const size_t kbase = ((size_t)b * S) * rowStride + h * E;

    const float scale = 0.125f;  // 1/sqrt(E)

    // ---- Q fragments, pre-scaled (A layout: m=lq, k = ks*32 + quad*8 + j) ----
    half8 qf[2];
    {
        const float* qp = Qg + qbase + (size_t)(q0 + wave*16 + lq) * rowStride + quad*8;
        #pragma unroll
        for (int ks = 0; ks < 2; ++ks)
            #pragma unroll
            for (int j = 0; j < 8; ++j)
                qf[ks][j] = (_Float16)(qp[ks*32 + j] * scale);
    }

    float mi[4], li[4];
    f32x4 oacc[4];
    #pragma unroll
    for (int r = 0; r < 4; ++r) { mi[r] = -1e30f; li[r] = 0.f; }
    #pragma unroll
    for (int nt = 0; nt < 4; ++nt) oacc[nt] = (f32x4){0.f, 0.f, 0.f, 0.f};

    // staging decomposition for the V 4x4 register transpose
    const int db = tid & 15;   // d-block (4 cols) — fast => coalesced global reads
    const int sb = tid >> 4;   // s-block (4 rows)

    for (int s0 = 0; s0 < S; s0 += BN) {
        // ---- K tile: float4 -> half4 vectorized stores (conflict-free) ----
        #pragma unroll
        for (int i = 0; i < 4; ++i) {
            int idx = i * 256 + tid;
            int r  = idx >> 4;
            int c  = (idx & 15) * 4;
            const float4 kv = *(const float4*)(Kg + kbase + (size_t)(s0 + r) * rowStride + c);
            half4 hk = {(_Float16)kv.x, (_Float16)kv.y, (_Float16)kv.z, (_Float16)kv.w};
            *(half4*)&sK[r][c] = hk;
        }
        // ---- V tile: 4x4 register transpose + XOR-swizzled stores ----
        // logical sV[d][sb*4+i] -> physical chunk (sb>>1)^(db&7), half off (sb&1)*4+i
        {
            const float* vp = Vg + kbase + (size_t)(s0 + sb*4) * rowStride + db*4;
            float4 vr[4];
            #pragma unroll
            for (int i = 0; i < 4; ++i)
                vr[i] = *(const float4*)(vp + (size_t)i * rowStride);
            const int sOff = (((sb >> 1) ^ (db & 7)) << 3) + ((sb & 1) << 2);
            #pragma unroll
            for (int j = 0; j < 4; ++j) {
                half4 hv = { (_Float16)((&vr[0].x)[j]), (_Float16)((&vr[1].x)[j]),
                             (_Float16)((&vr[2].x)[j]), (_Float16)((&vr[3].x)[j]) };
                *(half4*)&sV[db*4 + j][sOff] = hv;
            }
        }
        __syncthreads();

        // ---- S = Q K^T  (B-operand = K rows: n=lq, k contiguous) ----
        f32x4 sf[4];
        #pragma unroll
        for (int nt = 0; nt < 4; ++nt) {
            half8 kf0 = *(const half8*)&sK[nt*16 + lq][ 0 + quad*8];
            half8 kf1 = *(const half8*)&sK[nt*16 + lq][32 + quad*8];
            f32x4 acc = (f32x4){0.f, 0.f, 0.f, 0.f};
            acc = __builtin_amdgcn_mfma_f32_16x16x32_f16(qf[0], kf0, acc, 0, 0, 0);
            acc = __builtin_amdgcn_mfma_f32_16x16x32_f16(qf[1], kf1, acc, 0, 0, 0);
            sf[nt] = acc;
        }

        // ---- logits = scores_prescaled + scale*mask; C-layout: row=quad*4+r, col=nt*16+lq ----
        float lg[4][4];
        #pragma unroll
        for (int r = 0; r < 4; ++r) {
            const float* mrow = Mg + (size_t)(q0 + wave*16 + quad*4 + r) * S + s0;
            #pragma unroll
            for (int nt = 0; nt < 4; ++nt)
                lg[nt][r] = fmaf(scale, mrow[nt*16 + lq], sf[nt][r]);
        }

        // ---- online softmax (row stats live in the 16-lane quad) ----
        #pragma unroll
        for (int r = 0; r < 4; ++r) {
            float m = fmaxf(fmaxf(lg[0][r], lg[1][r]), fmaxf(lg[2][r], lg[3][r]));
            #pragma unroll
            for (int off = 1; off < 16; off <<= 1)
                m = fmaxf(m, __shfl_xor(m, off));
            float mnew  = fmaxf(mi[r], m);
            float alpha = __expf(mi[r] - mnew);
            mi[r] = mnew;
            float rs = 0.f;
            #pragma unroll
            for (int nt = 0; nt < 4; ++nt) {
                float p = __expf(lg[nt][r] - mnew);
                lg[nt][r] = p;
                rs += p;
            }
            #pragma unroll
            for (int off = 1; off < 16; off <<= 1)
                rs += __shfl_xor(rs, off);
            li[r] = li[r] * alpha + rs;
            oacc[0][r] *= alpha; oacc[1][r] *= alpha;
            oacc[2][r] *= alpha; oacc[3][r] *= alpha;
        }

        // ---- P -> LDS (C-layout -> A-operand layout round trip, per-wave region) ----
        #pragma unroll
        for (int nt = 0; nt < 4; ++nt)
            #pragma unroll
            for (int r = 0; r < 4; ++r)
                sP[wave][quad*4 + r][nt*16 + lq] = (_Float16)lg[nt][r];

        // ---- O += P V  (A = P rows from LDS; B = V^T rows, swizzle-decoded) ----
        #pragma unroll
        for (int ks = 0; ks < 2; ++ks) {
            half8 pf = *(const half8*)&sP[wave][lq][ks*32 + quad*8];
            #pragma unroll
            for (int nt = 0; nt < 4; ++nt) {
                const int vrow = nt*16 + lq;
                const int s8p  = (ks*4 + quad) ^ ((vrow >> 2) & 7);
                half8 vf = *(const half8*)&sV[vrow][s8p << 3];
                oacc[nt] = __builtin_amdgcn_mfma_f32_16x16x32_f16(pf, vf, oacc[nt], 0, 0, 0);
            }
        }
        __syncthreads();
    }

    // ---- epilogue: O /= l, store fp32 [B,L,H,D] ----
    #pragma unroll
    for (int r = 0; r < 4; ++r) {
        float inv = 1.f / li[r];
        float* orow = Og + qbase + (size_t)(q0 + wave*16 + quad*4 + r) * rowStride;
        #pragma unroll
        for (int nt = 0; nt < 4; ++nt)
            orow[nt*16 + lq] = oacc[nt][r] * inv;
    }
}

extern "C" void kernel_launch(void* const* d_in, const int* in_sizes, int n_in,
                              void* d_out, int out_size, void* d_ws, size_t ws_size,
                              hipStream_t stream) {
    const float* Qg = (const float*)d_in[0];
    const float* Kg = (const float*)d_in[1];
    const float* Vg = (const float*)d_in[2];
    const float* Mg = (const float*)d_in[3];
    float* Og = (float*)d_out;
    dim3 grid(L / BM, B * H);  // 32 q-blocks x 32 (b,h)
    fa_kernel<<<grid, 256, 0, stream>>>(Qg, Kg, Vg, Mg, Og);
}